// Round 1
// baseline (3893.383 us; speedup 1.0000x reference)
//
#include <hip/hip_runtime.h>

// HeteroGNN forward (SAGE mean-aggr, two relations), MI355X.
//
// Layout decisions:
//  - Segment SUMS are accumulated directly into d_out (agg_r at offset 0,
//    agg_u at offset Nr*64) — d_out is exactly (Nr+Nu)*64 floats.
//  - d_ws holds only the two degree arrays ((Nr+Nu) floats = 1 MB).
//  - transform_kernel then reads the agg row, scales by 1/max(deg,1),
//    applies lin_l/lin_r + bias + relu IN PLACE (row fully staged in LDS
//    before the overwrite, so aliasing is safe per-block).

// ---------------------------------------------------------------------------
// Edge scatter: 16 threads per edge, each thread moves one float4 per
// direction. Coalesced 256B row reads; scalar f32 atomics for the scatter.
// ---------------------------------------------------------------------------
__global__ void edge_scatter_kernel(
    const float* __restrict__ xu, const float* __restrict__ xr,
    const int* __restrict__ src, const int* __restrict__ dst,
    float* __restrict__ agg_r, float* __restrict__ agg_u,
    float* __restrict__ deg_r, float* __restrict__ deg_u,
    int nE)
{
    int tid  = blockIdx.x * blockDim.x + threadIdx.x;
    int e    = tid >> 4;
    if (e >= nE) return;
    int lane = tid & 15;

    int su = src[e];
    int dr = dst[e];

    if (lane == 0) {
        atomicAdd(&deg_r[dr], 1.0f);
        atomicAdd(&deg_u[su], 1.0f);
    }

    const float4 a = *reinterpret_cast<const float4*>(xu + ((long long)su << 6) + (lane << 2));
    const float4 b = *reinterpret_cast<const float4*>(xr + ((long long)dr << 6) + (lane << 2));

    float* pr = agg_r + ((long long)dr << 6) + (lane << 2);
    float* pu = agg_u + ((long long)su << 6) + (lane << 2);

    atomicAdd(pr + 0, a.x); atomicAdd(pr + 1, a.y);
    atomicAdd(pr + 2, a.z); atomicAdd(pr + 3, a.w);
    atomicAdd(pu + 0, b.x); atomicAdd(pu + 1, b.y);
    atomicAdd(pu + 2, b.z); atomicAdd(pu + 3, b.w);
}

// ---------------------------------------------------------------------------
// Row transform: out = relu( (agg/deg) @ Wl + bl + xroot @ Wr ).
// Block = 256 threads = 4 rows x 64 output features. Wl/Wr staged in LDS
// (32 KB), grid-stride over rows to amortize the staging.
// out may alias agg (in-place): the row is read into LDS and barriered
// before any thread writes it back.
// ---------------------------------------------------------------------------
__global__ void transform_kernel(
    const float* __restrict__ agg, const float* __restrict__ deg,
    const float* __restrict__ xroot,
    const float* __restrict__ Wl, const float* __restrict__ bl,
    const float* __restrict__ Wr,
    float* __restrict__ out, int N)
{
    __shared__ float sWl[64 * 64];
    __shared__ float sWr[64 * 64];
    __shared__ float sb[64];
    __shared__ float sAgg[4][64];
    __shared__ float sX[4][64];

    const int t = threadIdx.x;            // 0..255
    for (int i = t; i < 64 * 64; i += 256) {
        sWl[i] = Wl[i];
        sWr[i] = Wr[i];
    }
    if (t < 64) sb[t] = bl[t];
    __syncthreads();

    const int rg = t >> 6;    // row group 0..3
    const int h  = t & 63;    // output feature

    for (long long r0 = (long long)blockIdx.x * 4; r0 < N; r0 += (long long)gridDim.x * 4) {
        const long long r = r0 + rg;
        if (r < N) {
            const float inv = 1.0f / fmaxf(deg[r], 1.0f);
            sAgg[rg][h] = agg[(r << 6) + h] * inv;
            sX[rg][h]   = xroot[(r << 6) + h];
        }
        __syncthreads();
        if (r < N) {
            float acc = sb[h];
            #pragma unroll
            for (int d = 0; d < 64; ++d) {
                acc += sAgg[rg][d] * sWl[d * 64 + h] + sX[rg][d] * sWr[d * 64 + h];
            }
            out[(r << 6) + h] = fmaxf(acc, 0.0f);
        }
        __syncthreads();
    }
}

extern "C" void kernel_launch(void* const* d_in, const int* in_sizes, int n_in,
                              void* d_out, int out_size, void* d_ws, size_t ws_size,
                              hipStream_t stream)
{
    const float* xu    = (const float*)d_in[0];   // [Nu,64]
    const float* xr    = (const float*)d_in[1];   // [Nr,64]
    const int*   src   = (const int*)  d_in[2];   // [E]
    const int*   dst   = (const int*)  d_in[3];   // [E]
    const float* Wl_ur = (const float*)d_in[4];   // [64,64]
    const float* bl_ur = (const float*)d_in[5];   // [64]
    const float* Wr_ur = (const float*)d_in[6];   // [64,64]
    const float* Wl_ru = (const float*)d_in[7];   // [64,64]
    const float* bl_ru = (const float*)d_in[8];   // [64]
    const float* Wr_ru = (const float*)d_in[9];   // [64,64]

    const int Nu = in_sizes[0] / 64;
    const int Nr = in_sizes[1] / 64;
    const int nE = in_sizes[2];

    float* out   = (float*)d_out;
    float* agg_r = out;                          // [Nr*64] sums, then out_res
    float* agg_u = out + (long long)Nr * 64;     // [Nu*64] sums, then out_user
    float* deg_r = (float*)d_ws;                 // [Nr]
    float* deg_u = deg_r + Nr;                   // [Nu]

    // Zero the accumulators (d_out/d_ws are poisoned before every call).
    hipMemsetAsync(d_out, 0, (size_t)out_size * sizeof(float), stream);
    hipMemsetAsync(d_ws, 0, (size_t)(Nr + Nu) * sizeof(float), stream);

    // Edge aggregation (both relations fused).
    {
        const long long total = (long long)nE * 16;
        const int block = 256;
        const int grid  = (int)((total + block - 1) / block);
        edge_scatter_kernel<<<grid, block, 0, stream>>>(
            xu, xr, src, dst, agg_r, agg_u, deg_r, deg_u, nE);
    }

    // Per-row transforms (in place over the agg buffers).
    {
        const int block = 256;
        const int grid  = 2048;
        transform_kernel<<<grid, block, 0, stream>>>(
            agg_r, deg_r, xr, Wl_ur, bl_ur, Wr_ur, agg_r, Nr);
        transform_kernel<<<grid, block, 0, stream>>>(
            agg_u, deg_u, xu, Wl_ru, bl_ru, Wr_ru, agg_u, Nu);
    }
}

// Round 2
// 846.379 us; speedup vs baseline: 4.6000x; 4.6000x over previous
//
#include <hip/hip_runtime.h>

// HeteroGNN forward (SAGE mean-aggr, two relations), MI355X.
//
// Round 2: replace the f32-atomic scatter (4.2 GB of HBM RMW traffic, 3.56 ms)
// with an on-device CSR build + atomic-free gather-reduce.
//
//  Phase A (CSR build, all int32 in d_ws):
//    cnt[Nr+Nu]  <- per-node degree via int atomics (L2-resident, cheap)
//    off[Nr+Nu+1] <- exclusive scan of cnt (3-kernel hierarchical scan)
//    nbr[2E]     <- neighbor ids bucketed by node (atomicSub cursor on cnt)
//  Phase B: gather_mean — 16 lanes/node, float4 register accumulate,
//    one streaming write per output row (scaled by 1/max(deg,1)).
//  Phase C: in-place row transform out = relu(mean @ Wl + bl + x @ Wr).
//
//  Fallback: if ws_size < CSR requirement, use the round-1 atomic path.

// ---------------------------------------------------------------------------
// Phase A kernels
// ---------------------------------------------------------------------------
__global__ void count_kernel(const int* __restrict__ src, const int* __restrict__ dst,
                             int* __restrict__ cnt, int Nr, int nE)
{
    int e = blockIdx.x * blockDim.x + threadIdx.x;
    if (e >= nE) return;
    atomicAdd(&cnt[dst[e]], 1);          // resource buckets [0, Nr)
    atomicAdd(&cnt[Nr + src[e]], 1);     // user buckets     [Nr, Nr+Nu)
}

#define SCAN_BS 2048   // elements per block in scan (256 thr x 8)

__global__ void scan_block_kernel(const int* __restrict__ cnt, int* __restrict__ off,
                                  int* __restrict__ partial, int N)
{
    __shared__ int sdata[256];
    const int t = threadIdx.x;
    const long long base = (long long)blockIdx.x * SCAN_BS + (long long)t * 8;
    int v[8];
    int s = 0;
    #pragma unroll
    for (int k = 0; k < 8; ++k) {
        long long i = base + k;
        v[k] = (i < N) ? cnt[i] : 0;
        s += v[k];
    }
    sdata[t] = s;
    __syncthreads();
    for (int d = 1; d < 256; d <<= 1) {
        int val = (t >= d) ? sdata[t - d] : 0;
        __syncthreads();
        if (t >= d) sdata[t] += val;
        __syncthreads();
    }
    if (t == 255) partial[blockIdx.x] = sdata[255];
    int run = sdata[t] - s;   // exclusive prefix for this thread's chunk
    #pragma unroll
    for (int k = 0; k < 8; ++k) {
        long long i = base + k;
        if (i < N) off[i] = run;
        run += v[k];
    }
}

__global__ void scan_partials_kernel(int* __restrict__ partial, int nb)
{
    __shared__ int sdata[256];
    const int t = threadIdx.x;
    int v = (t < nb) ? partial[t] : 0;
    sdata[t] = v;
    __syncthreads();
    for (int d = 1; d < 256; d <<= 1) {
        int val = (t >= d) ? sdata[t - d] : 0;
        __syncthreads();
        if (t >= d) sdata[t] += val;
        __syncthreads();
    }
    if (t < nb) partial[t] = sdata[t] - v;   // exclusive
}

__global__ void scan_addback_kernel(int* __restrict__ off, const int* __restrict__ partial,
                                    int N, int total)
{
    long long i = (long long)blockIdx.x * blockDim.x + threadIdx.x;
    if (i < N) off[i] += partial[i / SCAN_BS];
    if (i == 0) off[N] = total;
}

__global__ void bucket_scatter_kernel(const int* __restrict__ src, const int* __restrict__ dst,
                                      const int* __restrict__ off, int* __restrict__ cnt,
                                      int* __restrict__ nbr, int Nr, int nE)
{
    int e = blockIdx.x * blockDim.x + threadIdx.x;
    if (e >= nE) return;
    const int su = src[e];
    const int dr = dst[e];
    // resource bucket dr gets neighbor su
    int p1 = off[dr] + atomicSub(&cnt[dr], 1) - 1;
    nbr[p1] = su;
    // user bucket su gets neighbor dr
    int p2 = off[Nr + su] + atomicSub(&cnt[Nr + su], 1) - 1;
    nbr[p2] = dr;
}

// ---------------------------------------------------------------------------
// Phase B: atomic-free gather + mean.  16 lanes per node; lane owns 4 feats.
// ---------------------------------------------------------------------------
__device__ __forceinline__ void f4add(float4& a, const float4 v) {
    a.x += v.x; a.y += v.y; a.z += v.z; a.w += v.w;
}

__global__ void gather_mean_kernel(const float* __restrict__ x,
                                   const int* __restrict__ off,
                                   const int* __restrict__ nbr,
                                   float* __restrict__ agg, int N)
{
    const int tid  = blockIdx.x * blockDim.x + threadIdx.x;
    const int g    = tid >> 4;
    if (g >= N) return;
    const int lane = tid & 15;
    const int c    = lane << 2;

    const int beg = off[g];
    const int end = off[g + 1];

    float4 a0 = {0,0,0,0}, a1 = {0,0,0,0}, a2 = {0,0,0,0}, a3 = {0,0,0,0};
    int j = beg;
    for (; j + 4 <= end; j += 4) {
        const int s0 = nbr[j], s1 = nbr[j+1], s2 = nbr[j+2], s3 = nbr[j+3];
        f4add(a0, *reinterpret_cast<const float4*>(x + ((long long)s0 << 6) + c));
        f4add(a1, *reinterpret_cast<const float4*>(x + ((long long)s1 << 6) + c));
        f4add(a2, *reinterpret_cast<const float4*>(x + ((long long)s2 << 6) + c));
        f4add(a3, *reinterpret_cast<const float4*>(x + ((long long)s3 << 6) + c));
    }
    for (; j < end; ++j) {
        f4add(a0, *reinterpret_cast<const float4*>(x + ((long long)nbr[j] << 6) + c));
    }
    f4add(a0, a1); f4add(a2, a3); f4add(a0, a2);

    const float inv = 1.0f / (float)max(end - beg, 1);
    float4 r; r.x = a0.x * inv; r.y = a0.y * inv; r.z = a0.z * inv; r.w = a0.w * inv;
    *reinterpret_cast<float4*>(agg + ((long long)g << 6) + c) = r;
}

// ---------------------------------------------------------------------------
// Fallback (round-1) atomic edge scatter
// ---------------------------------------------------------------------------
__global__ void edge_scatter_kernel(
    const float* __restrict__ xu, const float* __restrict__ xr,
    const int* __restrict__ src, const int* __restrict__ dst,
    float* __restrict__ agg_r, float* __restrict__ agg_u,
    float* __restrict__ deg_r, float* __restrict__ deg_u,
    int nE)
{
    int tid  = blockIdx.x * blockDim.x + threadIdx.x;
    int e    = tid >> 4;
    if (e >= nE) return;
    int lane = tid & 15;

    int su = src[e];
    int dr = dst[e];

    if (lane == 0) {
        atomicAdd(&deg_r[dr], 1.0f);
        atomicAdd(&deg_u[su], 1.0f);
    }
    const float4 a = *reinterpret_cast<const float4*>(xu + ((long long)su << 6) + (lane << 2));
    const float4 b = *reinterpret_cast<const float4*>(xr + ((long long)dr << 6) + (lane << 2));
    float* pr = agg_r + ((long long)dr << 6) + (lane << 2);
    float* pu = agg_u + ((long long)su << 6) + (lane << 2);
    atomicAdd(pr + 0, a.x); atomicAdd(pr + 1, a.y);
    atomicAdd(pr + 2, a.z); atomicAdd(pr + 3, a.w);
    atomicAdd(pu + 0, b.x); atomicAdd(pu + 1, b.y);
    atomicAdd(pu + 2, b.z); atomicAdd(pu + 3, b.w);
}

// ---------------------------------------------------------------------------
// Phase C: row transform, in place over agg.
//   out = relu( agg*(deg scale, optional) @ Wl + bl + x @ Wr )
// ---------------------------------------------------------------------------
__global__ void transform_kernel(
    const float* __restrict__ agg, const float* __restrict__ deg,
    const float* __restrict__ xroot,
    const float* __restrict__ Wl, const float* __restrict__ bl,
    const float* __restrict__ Wr,
    float* __restrict__ out, int N)
{
    __shared__ float sWl[64 * 64];
    __shared__ float sWr[64 * 64];
    __shared__ float sb[64];
    __shared__ float sAgg[4][64];
    __shared__ float sX[4][64];

    const int t = threadIdx.x;            // 0..255
    for (int i = t; i < 64 * 64; i += 256) {
        sWl[i] = Wl[i];
        sWr[i] = Wr[i];
    }
    if (t < 64) sb[t] = bl[t];
    __syncthreads();

    const int rg = t >> 6;
    const int h  = t & 63;

    for (long long r0 = (long long)blockIdx.x * 4; r0 < N; r0 += (long long)gridDim.x * 4) {
        const long long r = r0 + rg;
        if (r < N) {
            float inv = 1.0f;
            if (deg) inv = 1.0f / fmaxf(deg[r], 1.0f);
            sAgg[rg][h] = agg[(r << 6) + h] * inv;
            sX[rg][h]   = xroot[(r << 6) + h];
        }
        __syncthreads();
        if (r < N) {
            float acc = sb[h];
            #pragma unroll
            for (int d = 0; d < 64; ++d) {
                acc += sAgg[rg][d] * sWl[d * 64 + h] + sX[rg][d] * sWr[d * 64 + h];
            }
            out[(r << 6) + h] = fmaxf(acc, 0.0f);
        }
        __syncthreads();
    }
}

extern "C" void kernel_launch(void* const* d_in, const int* in_sizes, int n_in,
                              void* d_out, int out_size, void* d_ws, size_t ws_size,
                              hipStream_t stream)
{
    const float* xu    = (const float*)d_in[0];
    const float* xr    = (const float*)d_in[1];
    const int*   src   = (const int*)  d_in[2];
    const int*   dst   = (const int*)  d_in[3];
    const float* Wl_ur = (const float*)d_in[4];
    const float* bl_ur = (const float*)d_in[5];
    const float* Wr_ur = (const float*)d_in[6];
    const float* Wl_ru = (const float*)d_in[7];
    const float* bl_ru = (const float*)d_in[8];
    const float* Wr_ru = (const float*)d_in[9];

    const int Nu = in_sizes[0] / 64;
    const int Nr = in_sizes[1] / 64;
    const int nE = in_sizes[2];
    const int NN = Nr + Nu;

    float* out   = (float*)d_out;
    float* agg_r = out;                        // [Nr,64]
    float* agg_u = out + (long long)Nr * 64;   // [Nu,64]

    // ---- workspace layout (ints) ----
    int* cnt     = (int*)d_ws;                  // [NN]
    int* off     = cnt + NN;                    // [NN+1]
    int* partial = off + NN + 1;                // [256]
    int* nbr     = partial + 256;               // [2E]
    const size_t need = ((size_t)NN + (size_t)NN + 1 + 256 + 2ull * nE) * sizeof(int);

    if (ws_size >= need) {
        // ---------------- CSR path ----------------
        hipMemsetAsync(cnt, 0, (size_t)NN * sizeof(int), stream);

        const int eb = 256, eg = (nE + eb - 1) / eb;
        count_kernel<<<eg, eb, 0, stream>>>(src, dst, cnt, Nr, nE);

        const int nScanBlocks = (NN + SCAN_BS - 1) / SCAN_BS;   // <= 256
        scan_block_kernel<<<nScanBlocks, 256, 0, stream>>>(cnt, off, partial, NN);
        scan_partials_kernel<<<1, 256, 0, stream>>>(partial, nScanBlocks);
        scan_addback_kernel<<<(NN + 255) / 256, 256, 0, stream>>>(off, partial, NN, 2 * nE);

        bucket_scatter_kernel<<<eg, eb, 0, stream>>>(src, dst, off, cnt, nbr, Nr, nE);

        // gathers (mean fused in; writes every output row, no memset needed)
        {
            const long long tr = (long long)Nr * 16;
            gather_mean_kernel<<<(int)((tr + 255) / 256), 256, 0, stream>>>(
                xu, off, nbr, agg_r, Nr);
            const long long tu = (long long)Nu * 16;
            gather_mean_kernel<<<(int)((tu + 255) / 256), 256, 0, stream>>>(
                xr, off + Nr, nbr, agg_u, Nu);
        }

        transform_kernel<<<2048, 256, 0, stream>>>(
            agg_r, nullptr, xr, Wl_ur, bl_ur, Wr_ur, agg_r, Nr);
        transform_kernel<<<2048, 256, 0, stream>>>(
            agg_u, nullptr, xu, Wl_ru, bl_ru, Wr_ru, agg_u, Nu);
    } else {
        // ---------------- fallback: atomic path (round 1) ----------------
        float* deg_r = (float*)d_ws;
        float* deg_u = deg_r + Nr;
        hipMemsetAsync(d_out, 0, (size_t)out_size * sizeof(float), stream);
        hipMemsetAsync(d_ws, 0, (size_t)NN * sizeof(float), stream);

        const long long total = (long long)nE * 16;
        edge_scatter_kernel<<<(int)((total + 255) / 256), 256, 0, stream>>>(
            xu, xr, src, dst, agg_r, agg_u, deg_r, deg_u, nE);

        transform_kernel<<<2048, 256, 0, stream>>>(
            agg_r, deg_r, xr, Wl_ur, bl_ur, Wr_ur, agg_r, Nr);
        transform_kernel<<<2048, 256, 0, stream>>>(
            agg_u, deg_u, xu, Wl_ru, bl_ru, Wr_ru, agg_u, Nu);
    }
}